// Round 1
// baseline (971.160 us; speedup 1.0000x reference)
//
#include <hip/hip_runtime.h>
#include <cstdint>
#include <cstddef>

// Problem: B=16, S=2048, IN=1024, OUT=4096
// out[b,s,o] = sum_i x[b,s,i]*(W[o,i]-lr_b*G[o,i]) + bias[o]-lr_b*pbias[o]
#define PB   16
#define SEQ  2048
#define KIN  1024
#define NOUT 4096

#define BM 128
#define BN 128
#define BK 32

typedef __bf16 bf16x8 __attribute__((ext_vector_type(8)));
typedef float  f32x4  __attribute__((ext_vector_type(4)));

__device__ __forceinline__ unsigned short f2bf(float f) {
  union { float f; uint32_t u; } v; v.f = f;
  uint32_t u = v.u;
  u += 0x7fffu + ((u >> 16) & 1u);   // RNE
  return (unsigned short)(u >> 16);
}

__device__ __forceinline__ void async_copy16(const unsigned short* g, unsigned short* l) {
  __builtin_amdgcn_global_load_lds(
      (const __attribute__((address_space(1))) unsigned int*)g,
      (__attribute__((address_space(3))) unsigned int*)l,
      16, 0, 0);
}

// ---- kernel 1: x fp32 -> bf16 (8 elems/thread) ----------------------------
__global__ __launch_bounds__(256) void cvt_x_kernel(const float* __restrict__ x,
                                                    unsigned short* __restrict__ xb) {
  size_t i = ((size_t)blockIdx.x * 256 + threadIdx.x) * 8;
  float4 a = *(const float4*)(x + i);
  float4 b = *(const float4*)(x + i + 4);
  union { unsigned short s[8]; uint4 v; } p;
  p.s[0] = f2bf(a.x); p.s[1] = f2bf(a.y); p.s[2] = f2bf(a.z); p.s[3] = f2bf(a.w);
  p.s[4] = f2bf(b.x); p.s[5] = f2bf(b.y); p.s[6] = f2bf(b.z); p.s[7] = f2bf(b.w);
  *(uint4*)(xb + i) = p.v;
}

// ---- kernel 2: Wc[b][o][i] = bf16(W[o][i] - lr_b*G[o][i]), b innermost ----
__global__ __launch_bounds__(256) void cvt_w_kernel(const float* __restrict__ W,
                                                    const float* __restrict__ G,
                                                    const float* __restrict__ lrs,
                                                    unsigned short* __restrict__ wc) {
  size_t e = ((size_t)blockIdx.x * 256 + threadIdx.x) * 8;  // elem offset in [4096*1024]
  float4 w0 = *(const float4*)(W + e);
  float4 w1 = *(const float4*)(W + e + 4);
  float4 g0 = *(const float4*)(G + e);
  float4 g1 = *(const float4*)(G + e + 4);
  #pragma unroll
  for (int b = 0; b < PB; ++b) {
    float lr = lrs[b];
    union { unsigned short s[8]; uint4 v; } p;
    p.s[0] = f2bf(w0.x - lr * g0.x); p.s[1] = f2bf(w0.y - lr * g0.y);
    p.s[2] = f2bf(w0.z - lr * g0.z); p.s[3] = f2bf(w0.w - lr * g0.w);
    p.s[4] = f2bf(w1.x - lr * g1.x); p.s[5] = f2bf(w1.y - lr * g1.y);
    p.s[6] = f2bf(w1.z - lr * g1.z); p.s[7] = f2bf(w1.w - lr * g1.w);
    *(uint4*)(wc + (size_t)b * (size_t)NOUT * KIN + e) = p.v;
  }
}

// ---- kernel 3: batched GEMM out[b] = Xb @ Wc[b]^T + bias_eff --------------
// m97 structure: 128x128 tile, BK=32, 4 waves, 4x4 16x16x32 bf16 fragments,
// global_load_lds width=16 (wave-uniform LDS base + lane*16), 2-barrier K-loop.
__global__ __launch_bounds__(256, 2) void gemm_kernel(
    const unsigned short* __restrict__ xb,   // [16][2048][1024] bf16
    const unsigned short* __restrict__ wc,   // [16][4096][1024] bf16
    const float* __restrict__ bias,          // [4096]
    const float* __restrict__ pbias,         // [4096]
    const float* __restrict__ lrs,           // [16]
    float* __restrict__ out)                 // [16][2048][4096] fp32
{
  const int tid  = threadIdx.x;
  const int wave = tid >> 6;
  const int lane = tid & 63;
  const int quad = lane >> 4;
  const int l16  = lane & 15;
  const int wm   = wave >> 1;   // wave tile row (0..1)
  const int wn   = wave & 1;    // wave tile col (0..1)

  const int nt = blockIdx.x;    // 0..31  (OUT tiles)
  const int mt = blockIdx.y;    // 0..15  (SEQ tiles)
  const int b  = blockIdx.z;    // 0..15  (batch)

  __shared__ alignas(16) unsigned short As[BM][BK];  // 8 KiB, 64 B rows
  __shared__ alignas(16) unsigned short Bs[BN][BK];  // 8 KiB

  const unsigned short* xA = xb + ((size_t)b * SEQ  + (size_t)mt * BM) * KIN;
  const unsigned short* wB = wc + ((size_t)b * NOUT + (size_t)nt * BN) * KIN;

  // staging: each wave covers 16 rows per issue; 4 lanes per 64 B row
  const int srow = lane >> 2;   // 0..15
  const int sch  = lane & 3;    // 16 B chunk within row

  const unsigned short* gA0 = xA + (size_t)(wave * 16 + srow) * KIN + sch * 8;
  const unsigned short* gA1 = gA0 + (size_t)64 * KIN;
  const unsigned short* gB0 = wB + (size_t)(wave * 16 + srow) * KIN + sch * 8;
  const unsigned short* gB1 = gB0 + (size_t)64 * KIN;

  unsigned short* lA0 = &As[wave * 16][0];       // wave-uniform LDS base
  unsigned short* lA1 = &As[64 + wave * 16][0];
  unsigned short* lB0 = &Bs[wave * 16][0];
  unsigned short* lB1 = &Bs[64 + wave * 16][0];

  f32x4 acc[4][4];
  #pragma unroll
  for (int i = 0; i < 4; ++i)
    #pragma unroll
    for (int j = 0; j < 4; ++j)
      acc[i][j] = (f32x4){0.f, 0.f, 0.f, 0.f};

  for (int k0 = 0; k0 < KIN; k0 += BK) {
    __syncthreads();   // previous iter's compute done reading LDS
    async_copy16(gA0 + k0, lA0);
    async_copy16(gA1 + k0, lA1);
    async_copy16(gB0 + k0, lB0);
    async_copy16(gB1 + k0, lB1);
    __syncthreads();   // vmcnt(0) drain + barrier: staging visible

    bf16x8 af[4], bfr[4];
    #pragma unroll
    for (int f = 0; f < 4; ++f) {
      af[f]  = *(const bf16x8*)&As[wm * 64 + f * 16 + l16][quad * 8];
      bfr[f] = *(const bf16x8*)&Bs[wn * 64 + f * 16 + l16][quad * 8];
    }
    #pragma unroll
    for (int fm = 0; fm < 4; ++fm)
      #pragma unroll
      for (int fn = 0; fn < 4; ++fn)
        acc[fm][fn] = __builtin_amdgcn_mfma_f32_16x16x32_bf16(
            af[fm], bfr[fn], acc[fm][fn], 0, 0, 0);
  }

  // epilogue: C/D layout col=lane&15, row=quad*4+reg (m89-verified)
  const float lr = lrs[b];
  const int row0 = mt * BM + wm * 64;
  const int col0 = nt * BN + wn * 64;
  float* outB = out + (size_t)b * SEQ * NOUT;
  #pragma unroll
  for (int fn = 0; fn < 4; ++fn) {
    const int o = col0 + fn * 16 + l16;
    const float be = bias[o] - lr * pbias[o];
    #pragma unroll
    for (int fm = 0; fm < 4; ++fm) {
      const int r0 = row0 + fm * 16 + quad * 4;
      #pragma unroll
      for (int r = 0; r < 4; ++r)
        outB[(size_t)(r0 + r) * NOUT + o] = acc[fm][fn][r] + be;
    }
  }
}

extern "C" void kernel_launch(void* const* d_in, const int* in_sizes, int n_in,
                              void* d_out, int out_size, void* d_ws, size_t ws_size,
                              hipStream_t stream) {
  const float* x     = (const float*)d_in[0];  // [16,2048,1024]
  const float* W     = (const float*)d_in[1];  // [4096,1024]
  const float* bias  = (const float*)d_in[2];  // [4096]
  const float* G     = (const float*)d_in[3];  // [4096,1024]
  const float* pb    = (const float*)d_in[4];  // [4096]
  const float* lrs   = (const float*)d_in[5];  // [16]
  float* out = (float*)d_out;

  // workspace layout: xb (64 MiB bf16) | wc (128 MiB bf16) = 192 MiB
  unsigned short* xb = (unsigned short*)d_ws;
  unsigned short* wc = xb + (size_t)PB * SEQ * KIN;

  // x -> bf16: 33,554,432 elems / 2048 per block
  cvt_x_kernel<<<16384, 256, 0, stream>>>(x, xb);
  // Wc[b] = bf16(W - lr_b*G): 524,288 8-elem chunks / 256 per block
  cvt_w_kernel<<<2048, 256, 0, stream>>>(W, G, lrs, wc);

  dim3 grid(NOUT / BN, SEQ / BM, PB);  // (32, 16, 16) = 8192 blocks
  gemm_kernel<<<grid, 256, 0, stream>>>(xb, wc, bias, pb, lrs, out);
}